// Round 2
// baseline (128.338 us; speedup 1.0000x reference)
//
#include <hip/hip_runtime.h>
#include <hip/hip_bf16.h>
#include <hip/hip_fp16.h>

#define B_   4
#define C_   64
#define H_   128
#define W_   160
#define N_   9
#define HW_  (H_*W_)            // 20480
#define NPTS (B_*N_*H_*W_)      // 737280
#define EPS_ 1e-5f

// d_ws layout:
//   [0, TFEAT_BYTES):  f16 transposed features [B][H][W][C]
//   [TFEAT_BYTES, +289*4): fused f32 MLP weights:
//     fw0[16*8] @0, fb0[16] @128, fw1[8*16] @144, fb1[8] @272, fsim[8] @280, bsim @288
#define TFEAT_BYTES (B_*HW_*C_*2)   // 10,485,760

typedef _Float16 h2_t __attribute__((ext_vector_type(2)));
union U4 { uint4 u; h2_t h[4]; };

// Kernel A: [B,C,H,W] f32 -> [B,H,W,C] f16 tiled transpose; block 0 also fuses BN into MLP weights.
__global__ __launch_bounds__(256) void transpose_fuse(
    const float* __restrict__ feat,
    const float* __restrict__ w0, const float* __restrict__ g0, const float* __restrict__ b0,
    const float* __restrict__ m0, const float* __restrict__ v0,
    const float* __restrict__ w1, const float* __restrict__ g1, const float* __restrict__ b1,
    const float* __restrict__ m1, const float* __restrict__ v1,
    const float* __restrict__ wsim, const float* __restrict__ bsim,
    _Float16* __restrict__ tf, float* __restrict__ fw)
{
    __shared__ float tile[64][65];   // +1 pad: conflict-free transpose
    const int blk = blockIdx.x;      // 0..1279
    const int bi  = blk / 320;
    const int hw0 = (blk - bi * 320) * 64;
    const int t   = threadIdx.x;
    const int lhw = t & 63;
    const int cq  = t >> 6;          // 0..3

    const float* fb = feat + (size_t)bi * C_ * HW_;
    #pragma unroll
    for (int k = 0; k < 16; ++k) {
        int c = cq * 16 + k;
        tile[c][lhw] = fb[c * HW_ + hw0 + lhw];   // coalesced along hw
    }
    __syncthreads();
    const int c_out = t & 63;
    #pragma unroll
    for (int k = 0; k < 16; ++k) {
        int hw = cq * 16 + k;
        tf[((size_t)bi * HW_ + hw0 + hw) * C_ + c_out] =
            (_Float16)tile[c_out][hw];            // coalesced along c
    }

    if (blk == 0) {
        if (t < 16) {                       // layer0 rows
            float inv = g0[t] * rsqrtf(v0[t] + EPS_);
            for (int g = 0; g < 8; ++g) fw[t * 8 + g] = w0[t * 8 + g] * inv;
            fw[128 + t] = b0[t] - m0[t] * inv;
        } else if (t < 24) {                // layer1 rows
            int o = t - 16;
            float inv = g1[o] * rsqrtf(v1[o] + EPS_);
            for (int c = 0; c < 16; ++c) fw[144 + o * 16 + c] = w1[o * 16 + c] * inv;
            fw[272 + o] = b1[o] - m1[o] * inv;
        } else if (t == 24) {               // sim layer (no BN)
            for (int c = 0; c < 8; ++c) fw[280 + c] = wsim[c];
            fw[288] = bsim[0];
        }
    }
}

// Kernel B: 1 thread per output point. No LDS; MLP weights via wave-uniform s_loads.
__global__ __launch_bounds__(256) void fwnet_main(
    const float* __restrict__ grid, const _Float16* __restrict__ tf,
    const float* __restrict__ fw, float* __restrict__ out)
{
    // XCD-aware swizzle: 2880 blocks, 8 XCDs -> each XCD gets a contiguous 360-block
    // chunk (= half a batch of points) so its random taps stay in one 2.6MB image (L2-fit).
    const int bid  = blockIdx.x;
    const int sb   = (bid & 7) * (NPTS / 256 / 8) + (bid >> 3);
    const int p    = sb * 256 + threadIdx.x;

    // decode p -> (bi, h, px); grid row index == p / W_ by construction
    const int px  = p % W_;
    const int row = p / W_;
    const int bn  = row / H_;
    const int h   = row - bn * H_;
    const int bi  = bn / N_;

    const float2 gv = ((const float2*)grid)[p];
    float ix = fminf(fmaxf(((gv.x + 1.0f) * (float)W_ - 1.0f) * 0.5f, 0.0f), (float)(W_ - 1));
    float iy = fminf(fmaxf(((gv.y + 1.0f) * (float)H_ - 1.0f) * 0.5f, 0.0f), (float)(H_ - 1));
    float x0f = floorf(ix), y0f = floorf(iy);
    float wx = ix - x0f, wy = iy - y0f;
    int x0 = (int)x0f, y0 = (int)y0f;
    int x1 = min(x0 + 1, W_ - 1), y1 = min(y0 + 1, H_ - 1);
    float w00 = (1.0f - wx) * (1.0f - wy);
    float w01 = wx * (1.0f - wy);
    float w10 = (1.0f - wx) * wy;
    float w11 = wx * wy;

    const _Float16* Tb = tf + (size_t)bi * (HW_ * C_);
    const uint4* r00 = (const uint4*)(Tb + (y0 * W_ + x0) * C_);
    const uint4* r01 = (const uint4*)(Tb + (y0 * W_ + x1) * C_);
    const uint4* r10 = (const uint4*)(Tb + (y1 * W_ + x0) * C_);
    const uint4* r11 = (const uint4*)(Tb + (y1 * W_ + x1) * C_);
    const uint4* rrf = (const uint4*)(Tb + (h  * W_ + px) * C_);

    float wgt[8];
    #pragma unroll 2
    for (int g = 0; g < 8; ++g) {
        U4 t00, t01, t10, t11, trf;
        t00.u = r00[g]; t01.u = r01[g]; t10.u = r10[g]; t11.u = r11[g]; trf.u = rrf[g];
        float d00 = 0.f, d01 = 0.f, d10 = 0.f, d11 = 0.f;
        #pragma unroll
        for (int k = 0; k < 4; ++k) {
#if __has_builtin(__builtin_amdgcn_fdot2)
            d00 = __builtin_amdgcn_fdot2(t00.h[k], trf.h[k], d00, false);
            d01 = __builtin_amdgcn_fdot2(t01.h[k], trf.h[k], d01, false);
            d10 = __builtin_amdgcn_fdot2(t10.h[k], trf.h[k], d10, false);
            d11 = __builtin_amdgcn_fdot2(t11.h[k], trf.h[k], d11, false);
#else
            float rl = (float)trf.h[k].x, rh = (float)trf.h[k].y;
            d00 = fmaf((float)t00.h[k].x, rl, fmaf((float)t00.h[k].y, rh, d00));
            d01 = fmaf((float)t01.h[k].x, rl, fmaf((float)t01.h[k].y, rh, d01));
            d10 = fmaf((float)t10.h[k].x, rl, fmaf((float)t10.h[k].y, rh, d10));
            d11 = fmaf((float)t11.h[k].x, rl, fmaf((float)t11.h[k].y, rh, d11));
#endif
        }
        wgt[g] = (w00 * d00 + w01 * d01 + w10 * d10 + w11 * d11) * 0.125f;
    }

    // MLP: weights are wave-uniform (literal indices into fw) -> scalar loads.
    float h0[16];
    #pragma unroll
    for (int o = 0; o < 16; ++o) {
        float a = fw[128 + o];
        #pragma unroll
        for (int g = 0; g < 8; ++g) a = fmaf(fw[o * 8 + g], wgt[g], a);
        h0[o] = fmaxf(a, 0.0f);
    }
    float h1[8];
    #pragma unroll
    for (int o = 0; o < 8; ++o) {
        float a = fw[272 + o];
        #pragma unroll
        for (int c = 0; c < 16; ++c) a = fmaf(fw[144 + o * 16 + c], h0[c], a);
        h1[o] = fmaxf(a, 0.0f);
    }
    float s = fw[288];
    #pragma unroll
    for (int c = 0; c < 8; ++c) s = fmaf(fw[280 + c], h1[c], s);

    out[p] = 1.0f / (1.0f + __expf(-s));
}

extern "C" void kernel_launch(void* const* d_in, const int* in_sizes, int n_in,
                              void* d_out, int out_size, void* d_ws, size_t ws_size,
                              hipStream_t stream) {
    const float* feat = (const float*)d_in[0];
    const float* grid = (const float*)d_in[1];
    const float* w0   = (const float*)d_in[2];
    const float* g0   = (const float*)d_in[3];
    const float* b0   = (const float*)d_in[4];
    const float* m0   = (const float*)d_in[5];
    const float* v0   = (const float*)d_in[6];
    const float* w1   = (const float*)d_in[7];
    const float* g1   = (const float*)d_in[8];
    const float* b1   = (const float*)d_in[9];
    const float* m1   = (const float*)d_in[10];
    const float* v1   = (const float*)d_in[11];
    const float* wsim = (const float*)d_in[12];
    const float* bsim = (const float*)d_in[13];

    _Float16* tf = (_Float16*)d_ws;
    float* fw = (float*)((char*)d_ws + TFEAT_BYTES);

    hipLaunchKernelGGL(transpose_fuse, dim3(B_ * (HW_ / 64)), dim3(256), 0, stream,
                       feat, w0, g0, b0, m0, v0, w1, g1, b1, m1, v1, wsim, bsim, tf, fw);

    hipLaunchKernelGGL(fwnet_main, dim3(NPTS / 256), dim3(256), 0, stream,
                       grid, tf, fw, (float*)d_out);
}

// Round 3
// 41.809 us; speedup vs baseline: 3.0696x; 3.0696x over previous
//
#include <hip/hip_runtime.h>
#include <hip/hip_bf16.h>
#include <hip/hip_fp16.h>

#define B_   4
#define C_   64
#define H_   128
#define W_   160
#define N_   9
#define HW_  (H_*W_)            // 20480
#define NPTS (B_*N_*H_*W_)      // 737280
#define EPS_ 1e-5f

// d_ws layout:
//   [0, TFEAT_BYTES):  f16 transposed features [B][H][W][C]
//   [TFEAT_BYTES, +289*4): fused f32 MLP weights:
//     fw0[16*8] @0, fb0[16] @128, fw1[8*16] @144, fb1[8] @272, fsim[8] @280, bsim @288
#define TFEAT_BYTES (B_*HW_*C_*2)   // 10,485,760

typedef _Float16 h2_t __attribute__((ext_vector_type(2)));
union U4 { uint4 u; h2_t h[4]; };

// Kernel A: [B,C,H,W] f32 -> [B,H,W,C] f16 tiled transpose; block 0 also fuses BN into MLP weights.
__global__ __launch_bounds__(256) void transpose_fuse(
    const float* __restrict__ feat,
    const float* __restrict__ w0, const float* __restrict__ g0, const float* __restrict__ b0,
    const float* __restrict__ m0, const float* __restrict__ v0,
    const float* __restrict__ w1, const float* __restrict__ g1, const float* __restrict__ b1,
    const float* __restrict__ m1, const float* __restrict__ v1,
    const float* __restrict__ wsim, const float* __restrict__ bsim,
    _Float16* __restrict__ tf, float* __restrict__ fw)
{
    __shared__ float tile[64][65];   // +1 pad: conflict-free transpose
    const int blk = blockIdx.x;      // 0..1279
    const int bi  = blk / 320;
    const int hw0 = (blk - bi * 320) * 64;
    const int t   = threadIdx.x;
    const int lhw = t & 63;
    const int cq  = t >> 6;          // 0..3

    const float* fb = feat + (size_t)bi * C_ * HW_;
    #pragma unroll
    for (int k = 0; k < 16; ++k) {
        int c = cq * 16 + k;
        tile[c][lhw] = fb[c * HW_ + hw0 + lhw];   // coalesced along hw
    }
    __syncthreads();
    const int c_out = t & 63;
    #pragma unroll
    for (int k = 0; k < 16; ++k) {
        int hw = cq * 16 + k;
        tf[((size_t)bi * HW_ + hw0 + hw) * C_ + c_out] =
            (_Float16)tile[c_out][hw];            // coalesced along c
    }

    if (blk == 0) {
        if (t < 16) {                       // layer0 rows
            float inv = g0[t] * rsqrtf(v0[t] + EPS_);
            for (int g = 0; g < 8; ++g) fw[t * 8 + g] = w0[t * 8 + g] * inv;
            fw[128 + t] = b0[t] - m0[t] * inv;
        } else if (t < 24) {                // layer1 rows
            int o = t - 16;
            float inv = g1[o] * rsqrtf(v1[o] + EPS_);
            for (int c = 0; c < 16; ++c) fw[144 + o * 16 + c] = w1[o * 16 + c] * inv;
            fw[272 + o] = b1[o] - m1[o] * inv;
        } else if (t == 24) {               // sim layer (no BN)
            for (int c = 0; c < 8; ++c) fw[280 + c] = wsim[c];
            fw[288] = bsim[0];
        }
    }
}

// Kernel B: block = 256 threads = 256 points.
// Phase 1 (8 rounds): 8 lanes/point coalesced gather + fdot2 group-dots -> LDS.
// Phase 2: 1 thread/point MLP with wave-uniform (s_load) weights; coalesced store.
__global__ __launch_bounds__(256) void fwnet_main(
    const float* __restrict__ grid, const _Float16* __restrict__ tf,
    const float* __restrict__ fw, float* __restrict__ out)
{
    __shared__ float wlds[256 * 8];   // [point-in-block][group]

    const int t   = threadIdx.x;
    const int bid = blockIdx.x;
    // XCD swizzle: 2880 blocks, chunk 360/XCD -> contiguous 92160-point range per XCD
    const int sb    = (bid & 7) * (2880 / 8) + (bid >> 3);
    const int pbase = sb * 256;
    const int j     = t & 7;

    #pragma unroll 2
    for (int r = 0; r < 8; ++r) {
        const int q = r * 32 + (t >> 3);      // point-in-block
        const int p = pbase + q;

        const int px  = p % W_;
        const int row = p / W_;
        const int bn  = row / H_;
        const int h   = row - bn * H_;
        const int bi  = bn / N_;

        const float2 gv = ((const float2*)grid)[p];
        float ix = fminf(fmaxf(((gv.x + 1.0f) * (float)W_ - 1.0f) * 0.5f, 0.0f), (float)(W_ - 1));
        float iy = fminf(fmaxf(((gv.y + 1.0f) * (float)H_ - 1.0f) * 0.5f, 0.0f), (float)(H_ - 1));
        float x0f = floorf(ix), y0f = floorf(iy);
        float wx = ix - x0f, wy = iy - y0f;
        int x0 = (int)x0f, y0 = (int)y0f;
        int x1 = min(x0 + 1, W_ - 1), y1 = min(y0 + 1, H_ - 1);
        float w00 = (1.0f - wx) * (1.0f - wy);
        float w01 = wx * (1.0f - wy);
        float w10 = (1.0f - wx) * wy;
        float w11 = wx * wy;

        const _Float16* Tb = tf + (size_t)bi * (HW_ * C_);
        U4 a, b2, c2, d2, rr;
        a.u  = *((const uint4*)(Tb + (y0 * W_ + x0) * C_) + j);
        b2.u = *((const uint4*)(Tb + (y0 * W_ + x1) * C_) + j);
        c2.u = *((const uint4*)(Tb + (y1 * W_ + x0) * C_) + j);
        d2.u = *((const uint4*)(Tb + (y1 * W_ + x1) * C_) + j);
        rr.u = *((const uint4*)(Tb + (h  * W_ + px) * C_) + j);

        float d00 = 0.f, d01 = 0.f, d10 = 0.f, d11 = 0.f;
        #pragma unroll
        for (int k = 0; k < 4; ++k) {
#if __has_builtin(__builtin_amdgcn_fdot2)
            d00 = __builtin_amdgcn_fdot2(a.h[k],  rr.h[k], d00, false);
            d01 = __builtin_amdgcn_fdot2(b2.h[k], rr.h[k], d01, false);
            d10 = __builtin_amdgcn_fdot2(c2.h[k], rr.h[k], d10, false);
            d11 = __builtin_amdgcn_fdot2(d2.h[k], rr.h[k], d11, false);
#else
            d00 = fmaf((float)a.h[k].x,  (float)rr.h[k].x, fmaf((float)a.h[k].y,  (float)rr.h[k].y, d00));
            d01 = fmaf((float)b2.h[k].x, (float)rr.h[k].x, fmaf((float)b2.h[k].y, (float)rr.h[k].y, d01));
            d10 = fmaf((float)c2.h[k].x, (float)rr.h[k].x, fmaf((float)c2.h[k].y, (float)rr.h[k].y, d10));
            d11 = fmaf((float)d2.h[k].x, (float)rr.h[k].x, fmaf((float)d2.h[k].y, (float)rr.h[k].y, d11));
#endif
        }
        // linear LDS address: q*8 + j == r*256 + t  -> conflict-free write
        wlds[q * 8 + j] = (w00 * d00 + w01 * d01 + w10 * d10 + w11 * d11) * 0.125f;
    }
    __syncthreads();

    // Phase 2: thread t owns point pbase+t
    float wv[8];
    {
        const float4 lo = ((const float4*)wlds)[t * 2];
        const float4 hi = ((const float4*)wlds)[t * 2 + 1];
        wv[0] = lo.x; wv[1] = lo.y; wv[2] = lo.z; wv[3] = lo.w;
        wv[4] = hi.x; wv[5] = hi.y; wv[6] = hi.z; wv[7] = hi.w;
    }

    float h0[16];
    #pragma unroll
    for (int o = 0; o < 16; ++o) {
        float acc = fw[128 + o];
        #pragma unroll
        for (int g = 0; g < 8; ++g) acc = fmaf(fw[o * 8 + g], wv[g], acc);
        h0[o] = fmaxf(acc, 0.0f);
    }
    float h1[8];
    #pragma unroll
    for (int o = 0; o < 8; ++o) {
        float acc = fw[272 + o];
        #pragma unroll
        for (int c = 0; c < 16; ++c) acc = fmaf(fw[144 + o * 16 + c], h0[c], acc);
        h1[o] = fmaxf(acc, 0.0f);
    }
    float s = fw[288];
    #pragma unroll
    for (int c = 0; c < 8; ++c) s = fmaf(fw[280 + c], h1[c], s);

    out[pbase + t] = 1.0f / (1.0f + __expf(-s));
}

extern "C" void kernel_launch(void* const* d_in, const int* in_sizes, int n_in,
                              void* d_out, int out_size, void* d_ws, size_t ws_size,
                              hipStream_t stream) {
    const float* feat = (const float*)d_in[0];
    const float* grid = (const float*)d_in[1];
    const float* w0   = (const float*)d_in[2];
    const float* g0   = (const float*)d_in[3];
    const float* b0   = (const float*)d_in[4];
    const float* m0   = (const float*)d_in[5];
    const float* v0   = (const float*)d_in[6];
    const float* w1   = (const float*)d_in[7];
    const float* g1   = (const float*)d_in[8];
    const float* b1   = (const float*)d_in[9];
    const float* m1   = (const float*)d_in[10];
    const float* v1   = (const float*)d_in[11];
    const float* wsim = (const float*)d_in[12];
    const float* bsim = (const float*)d_in[13];

    _Float16* tf = (_Float16*)d_ws;
    float* fw = (float*)((char*)d_ws + TFEAT_BYTES);

    hipLaunchKernelGGL(transpose_fuse, dim3(B_ * (HW_ / 64)), dim3(256), 0, stream,
                       feat, w0, g0, b0, m0, v0, w1, g1, b1, m1, v1, wsim, bsim, tf, fw);

    hipLaunchKernelGGL(fwnet_main, dim3(NPTS / 256), dim3(256), 0, stream,
                       grid, tf, fw, (float*)d_out);
}

// Round 4
// 36.297 us; speedup vs baseline: 3.5358x; 1.1519x over previous
//
#include <hip/hip_runtime.h>
#include <hip/hip_bf16.h>
#include <hip/hip_fp16.h>

#define B_   4
#define C_   64
#define H_   128
#define W_   160
#define N_   9
#define HW_  (H_*W_)            // 20480
#define NPTS (B_*N_*H_*W_)      // 737280
#define EPS_ 1e-5f
#define ROWB (C_*2)             // 128 bytes per (h,w) feature row in f16

// d_ws layout:
//   [0, TFEAT_BYTES):  f16 transposed features [B][H][W][C]
//   [TFEAT_BYTES, +289*4): fused f32 MLP weights
#define TFEAT_BYTES (B_*HW_*C_*2)   // 10,485,760

typedef _Float16 h2_t __attribute__((ext_vector_type(2)));
union U4 { uint4 u; h2_t h[4]; };
union H2U { h2_t h; unsigned u; };

// Kernel A: [B,C,H,W] f32 -> [B,H,W,C] f16 tiled transpose; block 0 also fuses BN into MLP weights.
__global__ __launch_bounds__(256) void transpose_fuse(
    const float* __restrict__ feat,
    const float* __restrict__ w0, const float* __restrict__ g0, const float* __restrict__ b0,
    const float* __restrict__ m0, const float* __restrict__ v0,
    const float* __restrict__ w1, const float* __restrict__ g1, const float* __restrict__ b1,
    const float* __restrict__ m1, const float* __restrict__ v1,
    const float* __restrict__ wsim, const float* __restrict__ bsim,
    _Float16* __restrict__ tf, float* __restrict__ fw)
{
    __shared__ float tile[64][65];   // +1 pad
    const int blk = blockIdx.x;      // 0..1279
    const int bi  = blk / 320;
    const int hw0 = (blk - bi * 320) * 64;
    const int t   = threadIdx.x;
    const int lhw = t & 63;
    const int cq  = t >> 6;          // 0..3

    const float* fb = feat + (size_t)bi * C_ * HW_;
    #pragma unroll
    for (int k = 0; k < 16; ++k) {
        int c = cq * 16 + k;
        tile[c][lhw] = fb[c * HW_ + hw0 + lhw];   // coalesced along hw
    }
    __syncthreads();

    // store: thread packs 4 consecutive channels (8B); wave writes 512B contiguous
    const int c4 = (t & 15) * 4;
    #pragma unroll
    for (int k = 0; k < 4; ++k) {
        int hw = k * 16 + (t >> 4);
        H2U lo, hi;
        lo.h = h2_t{ (_Float16)tile[c4 + 0][hw], (_Float16)tile[c4 + 1][hw] };
        hi.h = h2_t{ (_Float16)tile[c4 + 2][hw], (_Float16)tile[c4 + 3][hw] };
        uint2 val; val.x = lo.u; val.y = hi.u;
        *(uint2*)(tf + ((size_t)bi * HW_ + hw0 + hw) * C_ + c4) = val;
    }

    if (blk == 0) {
        if (t < 16) {
            float inv = g0[t] * rsqrtf(v0[t] + EPS_);
            for (int g = 0; g < 8; ++g) fw[t * 8 + g] = w0[t * 8 + g] * inv;
            fw[128 + t] = b0[t] - m0[t] * inv;
        } else if (t < 24) {
            int o = t - 16;
            float inv = g1[o] * rsqrtf(v1[o] + EPS_);
            for (int c = 0; c < 16; ++c) fw[144 + o * 16 + c] = w1[o * 16 + c] * inv;
            fw[272 + o] = b1[o] - m1[o] * inv;
        } else if (t == 24) {
            for (int c = 0; c < 8; ++c) fw[280 + c] = wsim[c];
            fw[288] = bsim[0];
        }
    }
}

// Kernel B: block = 256 points.
// Phase 0: thread t -> coords/offsets for point pbase+t -> 32B LDS record.
// Phase 1 (8 rounds): 8 lanes/point coalesced gather + fdot2 -> wlds.
// Phase 2: thread t -> full MLP for its point, wave-uniform s_load weights.
__global__ __launch_bounds__(256) void fwnet_main(
    const float* __restrict__ grid, const _Float16* __restrict__ tf,
    const float* __restrict__ fw, float* __restrict__ out)
{
    __shared__ float wlds[256 * 8];  // 8 KB
    __shared__ int   rec[256 * 8];   // 8 KB: {wx, wy, o00, o01, o10, o11, orf, pad}

    const int t   = threadIdx.x;
    const int bid = blockIdx.x;
    // XCD swizzle: 2880 blocks, 360/XCD contiguous
    const int sb    = (bid & 7) * (2880 / 8) + (bid >> 3);
    const int pbase = sb * 256;

    // ---- phase 0: per-point coords ----
    {
        const int p   = pbase + t;
        const int px  = p % W_;
        const int row = p / W_;
        const int bn  = row / H_;
        const int h   = row - bn * H_;
        const int bi  = bn / N_;

        const float2 gv = ((const float2*)grid)[p];
        float ix = fminf(fmaxf(((gv.x + 1.0f) * (float)W_ - 1.0f) * 0.5f, 0.0f), (float)(W_ - 1));
        float iy = fminf(fmaxf(((gv.y + 1.0f) * (float)H_ - 1.0f) * 0.5f, 0.0f), (float)(H_ - 1));
        float x0f = floorf(ix), y0f = floorf(iy);
        float wx = ix - x0f, wy = iy - y0f;
        int x0 = (int)x0f, y0 = (int)y0f;
        int x1 = min(x0 + 1, W_ - 1), y1 = min(y0 + 1, H_ - 1);

        const int ib = bi * HW_;
        int4 rA, rB;
        rA.x = __float_as_int(wx);
        rA.y = __float_as_int(wy);
        rA.z = (ib + y0 * W_ + x0) * ROWB;
        rA.w = (ib + y0 * W_ + x1) * ROWB;
        rB.x = (ib + y1 * W_ + x0) * ROWB;
        rB.y = (ib + y1 * W_ + x1) * ROWB;
        rB.z = (ib + h  * W_ + px) * ROWB;
        rB.w = 0;
        ((int4*)rec)[t * 2]     = rA;
        ((int4*)rec)[t * 2 + 1] = rB;
    }
    __syncthreads();

    // ---- phase 1: gather + group dots ----
    const int j = t & 7;
    const char* base = (const char*)tf;
    #pragma unroll 2
    for (int r = 0; r < 8; ++r) {
        const int q = r * 32 + (t >> 3);
        const int4 rA = ((const int4*)rec)[q * 2];
        const int4 rB = ((const int4*)rec)[q * 2 + 1];
        const float wx = __int_as_float(rA.x);
        const float wy = __int_as_float(rA.y);
        const int jo = j * 16;

        U4 a, b2, c2, d2, rr;
        a.u  = *(const uint4*)(base + rA.z + jo);
        b2.u = *(const uint4*)(base + rA.w + jo);
        c2.u = *(const uint4*)(base + rB.x + jo);
        d2.u = *(const uint4*)(base + rB.y + jo);
        rr.u = *(const uint4*)(base + rB.z + jo);

        float d00 = 0.f, d01 = 0.f, d10 = 0.f, d11 = 0.f;
        #pragma unroll
        for (int k = 0; k < 4; ++k) {
#if __has_builtin(__builtin_amdgcn_fdot2)
            d00 = __builtin_amdgcn_fdot2(a.h[k],  rr.h[k], d00, false);
            d01 = __builtin_amdgcn_fdot2(b2.h[k], rr.h[k], d01, false);
            d10 = __builtin_amdgcn_fdot2(c2.h[k], rr.h[k], d10, false);
            d11 = __builtin_amdgcn_fdot2(d2.h[k], rr.h[k], d11, false);
#else
            d00 = fmaf((float)a.h[k].x,  (float)rr.h[k].x, fmaf((float)a.h[k].y,  (float)rr.h[k].y, d00));
            d01 = fmaf((float)b2.h[k].x, (float)rr.h[k].x, fmaf((float)b2.h[k].y, (float)rr.h[k].y, d01));
            d10 = fmaf((float)c2.h[k].x, (float)rr.h[k].x, fmaf((float)c2.h[k].y, (float)rr.h[k].y, d10));
            d11 = fmaf((float)d2.h[k].x, (float)rr.h[k].x, fmaf((float)d2.h[k].y, (float)rr.h[k].y, d11));
#endif
        }
        float dy0 = d00 + wx * (d01 - d00);
        float dy1 = d10 + wx * (d11 - d10);
        wlds[q * 8 + j] = (dy0 + wy * (dy1 - dy0)) * 0.125f;   // linear addr r*256+t
    }
    __syncthreads();

    // ---- phase 2: MLP per point ----
    float wv[8];
    {
        const float4 lo = ((const float4*)wlds)[t * 2];
        const float4 hi = ((const float4*)wlds)[t * 2 + 1];
        wv[0] = lo.x; wv[1] = lo.y; wv[2] = lo.z; wv[3] = lo.w;
        wv[4] = hi.x; wv[5] = hi.y; wv[6] = hi.z; wv[7] = hi.w;
    }

    float h0[16];
    #pragma unroll
    for (int o = 0; o < 16; ++o) {
        float acc = fw[128 + o];
        #pragma unroll
        for (int g = 0; g < 8; ++g) acc = fmaf(fw[o * 8 + g], wv[g], acc);
        h0[o] = fmaxf(acc, 0.0f);
    }
    float h1[8];
    #pragma unroll
    for (int o = 0; o < 8; ++o) {
        float acc = fw[272 + o];
        #pragma unroll
        for (int c = 0; c < 16; ++c) acc = fmaf(fw[144 + o * 16 + c], h0[c], acc);
        h1[o] = fmaxf(acc, 0.0f);
    }
    float s = fw[288];
    #pragma unroll
    for (int c = 0; c < 8; ++c) s = fmaf(fw[280 + c], h1[c], s);

    out[pbase + t] = 1.0f / (1.0f + __expf(-s));
}

extern "C" void kernel_launch(void* const* d_in, const int* in_sizes, int n_in,
                              void* d_out, int out_size, void* d_ws, size_t ws_size,
                              hipStream_t stream) {
    const float* feat = (const float*)d_in[0];
    const float* grid = (const float*)d_in[1];
    const float* w0   = (const float*)d_in[2];
    const float* g0   = (const float*)d_in[3];
    const float* b0   = (const float*)d_in[4];
    const float* m0   = (const float*)d_in[5];
    const float* v0   = (const float*)d_in[6];
    const float* w1   = (const float*)d_in[7];
    const float* g1   = (const float*)d_in[8];
    const float* b1   = (const float*)d_in[9];
    const float* m1   = (const float*)d_in[10];
    const float* v1   = (const float*)d_in[11];
    const float* wsim = (const float*)d_in[12];
    const float* bsim = (const float*)d_in[13];

    _Float16* tf = (_Float16*)d_ws;
    float* fw = (float*)((char*)d_ws + TFEAT_BYTES);

    hipLaunchKernelGGL(transpose_fuse, dim3(B_ * (HW_ / 64)), dim3(256), 0, stream,
                       feat, w0, g0, b0, m0, v0, w1, g1, b1, m1, v1, wsim, bsim, tf, fw);

    hipLaunchKernelGGL(fwnet_main, dim3(NPTS / 256), dim3(256), 0, stream,
                       grid, tf, fw, (float*)d_out);
}